// Round 1
// baseline (3329.581 us; speedup 1.0000x reference)
//
#include <hip/hip_runtime.h>
#include <math.h>

#define NPAPER 100000
#define NAUTH  50000
#define DIM    128
#define NEDGE  500000
#define NCLS   16

// ---------------------------------------------------------------------------
// Weight prep: build concatenated B matrices (K-major) so each fused transform
// is a single GEMM.  Bp[l] : [384][128], k-major, = [Wl0^T ; Wl1^T ; (Wr0+Wr1)^T]
//                    Ba[l] : [256][128] = [Wl2^T ; Wr2^T]
//                    LP    : [128][128] = I + lin_paper^T, LA likewise
__global__ __launch_bounds__(256) void prep_weights(
    const float* __restrict__ Wl, const float* __restrict__ Wr,
    const float* __restrict__ bl,
    const float* __restrict__ linp, const float* __restrict__ lina,
    float* __restrict__ Bp, float* __restrict__ Ba,
    float* __restrict__ LP, float* __restrict__ LA,
    float* __restrict__ biasp, float* __restrict__ biasa)
{
    int t = blockIdx.x * 256 + threadIdx.x;
    if (t < 2*384*128) {
        int l = t / (384*128); int rem = t - l*(384*128);
        int k = rem >> 7, j = rem & 127;
        float v;
        if (k < 128)      v = Wl[((l*3+0)*128 + j)*128 + k];
        else if (k < 256) v = Wl[((l*3+1)*128 + j)*128 + (k-128)];
        else              v = Wr[((l*3+0)*128 + j)*128 + (k-256)]
                            + Wr[((l*3+1)*128 + j)*128 + (k-256)];
        Bp[t] = v;
        return;
    }
    t -= 2*384*128;
    if (t < 2*256*128) {
        int l = t / (256*128); int rem = t - l*(256*128);
        int k = rem >> 7, j = rem & 127;
        Ba[t] = (k < 128) ? Wl[((l*3+2)*128 + j)*128 + k]
                          : Wr[((l*3+2)*128 + j)*128 + (k-128)];
        return;
    }
    t -= 2*256*128;
    if (t < 16384) { int k=t>>7, j=t&127; LP[t] = linp[j*128+k] + (k==j ? 1.f : 0.f); return; }
    t -= 16384;
    if (t < 16384) { int k=t>>7, j=t&127; LA[t] = lina[j*128+k] + (k==j ? 1.f : 0.f); return; }
    t -= 16384;
    if (t < 256) { int l=t>>7, j=t&127; biasp[t] = bl[(l*3+0)*128+j] + bl[(l*3+1)*128+j]; return; }
    t -= 256;
    if (t < 256) { int l=t>>7, j=t&127; biasa[t] = bl[(l*3+2)*128+j]; return; }
}

// ---------------------------------------------------------------------------
// Scatter-add aggregation: one wave (64 lanes) per edge; lane handles 2 floats.
__global__ __launch_bounds__(256) void scatter_agg(
    const float* __restrict__ xsrc, const int* __restrict__ ei,
    float* __restrict__ agg, float* __restrict__ cnt)
{
    int gw   = (blockIdx.x * 256 + threadIdx.x) >> 6;
    int lane = threadIdx.x & 63;
    if (gw >= NEDGE) return;
    int src = ei[gw];
    int dst = ei[NEDGE + gw];
    const float2 v = ((const float2*)(xsrc + (size_t)src * DIM))[lane];
    float* ag = agg + (size_t)dst * DIM + lane * 2;
    atomicAdd(ag,     v.x);
    atomicAdd(ag + 1, v.y);
    if (lane == 0) atomicAdd(cnt + dst, 1.0f);
}

// ---------------------------------------------------------------------------
// Fused GEMM:  out[N][128] = concat(A-segments)[N][K] @ B[K][128] (+bias)
// Segment s covers k in [128*s, 128*s+128); if its cnt ptr != null the rows are
// divided by max(cnt,1) (mean aggregation) while staging.
// Block = 256 threads, 32 rows per block, BK = 32.  In-place (out == A0) is
// safe: each block reads only its own 32 rows and writes them at the end.
__global__ __launch_bounds__(256) void gemm_fused(
    const float* __restrict__ A0, const float* __restrict__ c0,
    const float* __restrict__ A1, const float* __restrict__ c1,
    const float* __restrict__ A2, const float* __restrict__ c2,
    int nseg, int N,
    const float* __restrict__ B, int K,
    const float* __restrict__ bias,
    float* __restrict__ out)
{
    __shared__ float As[32*33];
    __shared__ float Bs[32*132];
    __shared__ float invc[3*32];

    int t    = threadIdx.x;
    int row0 = blockIdx.x * 32;
    int tc = t & 31, tr = t >> 5;

    if (t < 96) {
        int s = t >> 5, r = t & 31;
        const float* cp = (s==0) ? c0 : ((s==1) ? c1 : c2);
        float iv = 1.f;
        if (s < nseg && cp) {
            int gr = row0 + r;
            float cv = (gr < N) ? cp[gr] : 1.f;
            iv = 1.f / fmaxf(cv, 1.f);
        }
        invc[t] = iv;
    }
    __syncthreads();

    float acc[4][4] = {};

    for (int kk = 0; kk < K; kk += 32) {
        int seg = kk >> 7, kl = kk & 127;
        const float* Ap = (seg==0) ? A0 : ((seg==1) ? A1 : A2);
        #pragma unroll
        for (int i = 0; i < 4; i++) {
            int s = t + i*256; int r = s >> 5, k = s & 31;
            int gr = row0 + r;
            float v = (gr < N) ? Ap[(size_t)gr*DIM + kl + k] : 0.f;
            As[r*33 + k] = v * invc[seg*32 + r];
        }
        #pragma unroll
        for (int i = 0; i < 4; i++) {
            int s = t + i*256; int k = s >> 5, j4 = s & 31;
            float4 v = *(const float4*)(B + (size_t)(kk + k)*DIM + j4*4);
            *(float4*)(&Bs[k*132 + j4*4]) = v;
        }
        __syncthreads();
        #pragma unroll
        for (int k = 0; k < 32; k++) {
            float4 b4 = *(const float4*)(&Bs[k*132 + tc*4]);
            #pragma unroll
            for (int i = 0; i < 4; i++) {
                float a = As[(tr*4 + i)*33 + k];
                acc[i][0] += a * b4.x;
                acc[i][1] += a * b4.y;
                acc[i][2] += a * b4.z;
                acc[i][3] += a * b4.w;
            }
        }
        __syncthreads();
    }

    #pragma unroll
    for (int i = 0; i < 4; i++) {
        int gr = row0 + tr*4 + i;
        if (gr < N) {
            float4 v;
            v.x = acc[i][0]; v.y = acc[i][1]; v.z = acc[i][2]; v.w = acc[i][3];
            if (bias) {
                v.x += bias[tc*4+0]; v.y += bias[tc*4+1];
                v.z += bias[tc*4+2]; v.w += bias[tc*4+3];
            }
            *(float4*)(out + (size_t)gr*DIM + tc*4) = v;
        }
    }
}

// ---------------------------------------------------------------------------
// LayerNorm + ReLU, one wave per row (2 floats/lane), width-64 shuffle reduce.
__global__ __launch_bounds__(256) void ln_relu(
    const float* __restrict__ src, float* __restrict__ dst, int N,
    const float* __restrict__ g, const float* __restrict__ b)
{
    int wid  = (blockIdx.x * 256 + threadIdx.x) >> 6;
    int lane = threadIdx.x & 63;
    if (wid >= N) return;
    float2 v = ((const float2*)(src + (size_t)wid * DIM))[lane];
    float s  = v.x + v.y;
    float sq = v.x*v.x + v.y*v.y;
    #pragma unroll
    for (int o = 32; o; o >>= 1) { s += __shfl_xor(s, o); sq += __shfl_xor(sq, o); }
    float m   = s * (1.f/128.f);
    float var = sq * (1.f/128.f) - m*m;
    float r   = rsqrtf(var + 1e-5f);
    float y0 = (v.x - m) * r * g[2*lane]   + b[2*lane];
    float y1 = (v.y - m) * r * g[2*lane+1] + b[2*lane+1];
    float2 o2; o2.x = fmaxf(y0, 0.f); o2.y = fmaxf(y1, 0.f);
    ((float2*)(dst + (size_t)wid * DIM))[lane] = o2;
}

// ---------------------------------------------------------------------------
// Head: out[N][16] = xp[N][128] @ Wh[128][16] + bh.  16 rows/block.
__global__ __launch_bounds__(256) void head_kernel(
    const float* __restrict__ xp, const float* __restrict__ Wh,
    const float* __restrict__ bh, float* __restrict__ out)
{
    __shared__ float Xs[16*128];
    __shared__ float Ws[128*16];
    int t = threadIdx.x;
    int row0 = blockIdx.x * 16;
    for (int i = t; i < 2048; i += 256) Ws[i] = Wh[i];
    #pragma unroll
    for (int i = 0; i < 8; i++) {
        int s = t + i*256; int r = s >> 7, k = s & 127;
        int gr = row0 + r;
        Xs[s] = (gr < NPAPER) ? xp[(size_t)gr*DIM + k] : 0.f;
    }
    __syncthreads();
    int r = t >> 4, c = t & 15;
    float acc = bh[c];
    #pragma unroll 16
    for (int k = 0; k < 128; k++) acc += Xs[r*128 + k] * Ws[k*16 + c];
    int gr = row0 + r;
    if (gr < NPAPER) out[(size_t)gr*NCLS + c] = acc;
}

// ---------------------------------------------------------------------------
extern "C" void kernel_launch(void* const* d_in, const int* in_sizes, int n_in,
                              void* d_out, int out_size, void* d_ws, size_t ws_size,
                              hipStream_t stream)
{
    const float* x_paper  = (const float*)d_in[0];
    const float* x_author = (const float*)d_in[1];
    const int*   ei_cites = (const int*)d_in[2];
    const int*   ei_writes= (const int*)d_in[3];
    const int*   ei_rev   = (const int*)d_in[4];
    const float* Wl       = (const float*)d_in[5];
    const float* Wr       = (const float*)d_in[6];
    const float* bl       = (const float*)d_in[7];
    const float* linp     = (const float*)d_in[8];
    const float* lina     = (const float*)d_in[9];
    const float* ln_s     = (const float*)d_in[10];
    const float* ln_b     = (const float*)d_in[11];
    const float* Wh       = (const float*)d_in[12];
    const float* bh       = (const float*)d_in[13];
    float* out = (float*)d_out;

    float* ws = (float*)d_ws;
    size_t off = 0;
    float* xp    = ws + off; off += (size_t)NPAPER * DIM;
    float* xa    = ws + off; off += (size_t)NAUTH  * DIM;
    float* aggC  = ws + off; off += (size_t)NPAPER * DIM;
    float* aggW  = ws + off; off += (size_t)NPAPER * DIM;
    float* aggR  = ws + off; off += (size_t)NAUTH  * DIM;
    float* cntC  = ws + off; off += NPAPER;
    float* cntW  = ws + off; off += NPAPER;
    float* cntR  = ws + off; off += NAUTH;
    float* Bp    = ws + off; off += 2*384*128;
    float* Ba    = ws + off; off += 2*256*128;
    float* LP    = ws + off; off += 128*128;
    float* LA    = ws + off; off += 128*128;
    float* biasp = ws + off; off += 2*128;
    float* biasa = ws + off; off += 2*128;

    prep_weights<<<(197120 + 255)/256, 256, 0, stream>>>(
        Wl, Wr, bl, linp, lina, Bp, Ba, LP, LA, biasp, biasa);

    for (int l = 0; l < 2; l++) {
        const float* cur_p = (l == 0) ? x_paper  : xp;
        const float* cur_a = (l == 0) ? x_author : xa;

        hipMemsetAsync(aggC, 0, (size_t)NPAPER*DIM*4, stream);
        hipMemsetAsync(aggW, 0, (size_t)NPAPER*DIM*4, stream);
        hipMemsetAsync(aggR, 0, (size_t)NAUTH *DIM*4, stream);
        hipMemsetAsync(cntC, 0, (size_t)NPAPER*4, stream);
        hipMemsetAsync(cntW, 0, (size_t)NPAPER*4, stream);
        hipMemsetAsync(cntR, 0, (size_t)NAUTH *4, stream);

        scatter_agg<<<NEDGE/4, 256, 0, stream>>>(cur_p, ei_cites,  aggC, cntC);
        scatter_agg<<<NEDGE/4, 256, 0, stream>>>(cur_a, ei_writes, aggW, cntW);
        scatter_agg<<<NEDGE/4, 256, 0, stream>>>(cur_p, ei_rev,    aggR, cntR);

        // paper: [meanC | meanW | x_p] (K=384) @ Bp[l]  -> aggC (in-place safe)
        gemm_fused<<<(NPAPER+31)/32, 256, 0, stream>>>(
            aggC, cntC, aggW, cntW, cur_p, nullptr, 3, NPAPER,
            Bp + (size_t)l*384*128, 384, biasp + l*128, aggC);
        // author: [meanR | x_a] (K=256) @ Ba[l] -> aggR
        gemm_fused<<<(NAUTH+31)/32, 256, 0, stream>>>(
            aggR, cntR, cur_a, nullptr, nullptr, nullptr, 2, NAUTH,
            Ba + (size_t)l*256*128, 256, biasa + l*128, aggR);

        if (l == 0) {
            // residual: p = p @ (I + lin^T), in-place
            gemm_fused<<<(NPAPER+31)/32, 256, 0, stream>>>(
                aggC, nullptr, nullptr, nullptr, nullptr, nullptr, 1, NPAPER,
                LP, 128, nullptr, aggC);
            gemm_fused<<<(NAUTH+31)/32, 256, 0, stream>>>(
                aggR, nullptr, nullptr, nullptr, nullptr, nullptr, 1, NAUTH,
                LA, 128, nullptr, aggR);
        }

        ln_relu<<<NPAPER/4, 256, 0, stream>>>(aggC, xp, NPAPER,
                                              ln_s + (l*2+0)*128, ln_b + (l*2+0)*128);
        ln_relu<<<NAUTH/4, 256, 0, stream>>>(aggR, xa, NAUTH,
                                             ln_s + (l*2+1)*128, ln_b + (l*2+1)*128);
    }

    head_kernel<<<(NPAPER+15)/16, 256, 0, stream>>>(xp, Wh, bh, out);
}

// Round 2
// 1287.927 us; speedup vs baseline: 2.5852x; 2.5852x over previous
//
#include <hip/hip_runtime.h>
#include <math.h>

#define NPAPER 100000
#define NAUTH  50000
#define DIM    128
#define NEDGE  500000
#define NCLS   16

// ---------------------------------------------------------------------------
// Weight prep (unchanged): Bp[l]: [384][128] k-major = [Wl0^T; Wl1^T; (Wr0+Wr1)^T]
//                          Ba[l]: [256][128] = [Wl2^T; Wr2^T]
//                          LP = I + lin_paper^T, LA likewise
__global__ __launch_bounds__(256) void prep_weights(
    const float* __restrict__ Wl, const float* __restrict__ Wr,
    const float* __restrict__ bl,
    const float* __restrict__ linp, const float* __restrict__ lina,
    float* __restrict__ Bp, float* __restrict__ Ba,
    float* __restrict__ LP, float* __restrict__ LA,
    float* __restrict__ biasp, float* __restrict__ biasa)
{
    int t = blockIdx.x * 256 + threadIdx.x;
    if (t < 2*384*128) {
        int l = t / (384*128); int rem = t - l*(384*128);
        int k = rem >> 7, j = rem & 127;
        float v;
        if (k < 128)      v = Wl[((l*3+0)*128 + j)*128 + k];
        else if (k < 256) v = Wl[((l*3+1)*128 + j)*128 + (k-128)];
        else              v = Wr[((l*3+0)*128 + j)*128 + (k-256)]
                            + Wr[((l*3+1)*128 + j)*128 + (k-256)];
        Bp[t] = v;
        return;
    }
    t -= 2*384*128;
    if (t < 2*256*128) {
        int l = t / (256*128); int rem = t - l*(256*128);
        int k = rem >> 7, j = rem & 127;
        Ba[t] = (k < 128) ? Wl[((l*3+2)*128 + j)*128 + k]
                          : Wr[((l*3+2)*128 + j)*128 + (k-128)];
        return;
    }
    t -= 2*256*128;
    if (t < 16384) { int k=t>>7, j=t&127; LP[t] = linp[j*128+k] + (k==j ? 1.f : 0.f); return; }
    t -= 16384;
    if (t < 16384) { int k=t>>7, j=t&127; LA[t] = lina[j*128+k] + (k==j ? 1.f : 0.f); return; }
    t -= 16384;
    if (t < 256) { int l=t>>7, j=t&127; biasp[t] = bl[(l*3+0)*128+j] + bl[(l*3+1)*128+j]; return; }
    t -= 256;
    if (t < 256) { int l=t>>7, j=t&127; biasa[t] = bl[(l*3+2)*128+j]; return; }
}

// ---------------------------------------------------------------------------
// CSR build.  Step 1: degree histogram over dst ids.
__global__ __launch_bounds__(256) void deg_count(const int* __restrict__ ei,
                                                 int* __restrict__ deg)
{
    int i = blockIdx.x * 256 + threadIdx.x;
    if (i < NEDGE) atomicAdd(&deg[ei[NEDGE + i]], 1);
}

// Step 2a: per-1024-block exclusive scan + block sums.
__global__ __launch_bounds__(256) void scan_pass1(const int* __restrict__ in, int n,
                                                  int* __restrict__ out,
                                                  int* __restrict__ bsum)
{
    __shared__ int lds[256];
    int b0 = blockIdx.x * 1024;
    int t  = threadIdx.x;
    int v[4]; int s = 0;
    #pragma unroll
    for (int i = 0; i < 4; i++) {
        int idx = b0 + t*4 + i;
        v[i] = (idx < n) ? in[idx] : 0;
        s += v[i];
    }
    lds[t] = s;
    __syncthreads();
    for (int o = 1; o < 256; o <<= 1) {
        int x = (t >= o) ? lds[t - o] : 0;
        __syncthreads();
        lds[t] += x;
        __syncthreads();
    }
    int run = (t > 0) ? lds[t-1] : 0;
    if (t == 255) bsum[blockIdx.x] = lds[255];
    #pragma unroll
    for (int i = 0; i < 4; i++) {
        int idx = b0 + t*4 + i;
        if (idx < n) out[idx] = run;
        run += v[i];
    }
}

// Step 2b: scan the block sums (single block; nb <= 256).
__global__ __launch_bounds__(256) void scan_pass2(int* __restrict__ bsum, int nb)
{
    __shared__ int lds[256];
    int t = threadIdx.x;
    lds[t] = (t < nb) ? bsum[t] : 0;
    __syncthreads();
    for (int o = 1; o < 256; o <<= 1) {
        int x = (t >= o) ? lds[t - o] : 0;
        __syncthreads();
        lds[t] += x;
        __syncthreads();
    }
    if (t < nb) bsum[t] = (t > 0) ? lds[t-1] : 0;
}

// Step 2c: add block offsets, init cursor, set rowptr[n] = E.
__global__ __launch_bounds__(256) void scan_pass3(int* __restrict__ out, int n,
                                                  const int* __restrict__ bsum,
                                                  int* __restrict__ cursor)
{
    int i = blockIdx.x * 256 + threadIdx.x;
    if (i < n) {
        int v = out[i] + bsum[i >> 10];
        out[i] = v;
        cursor[i] = v;
    }
    if (i == n) out[n] = NEDGE;
}

// Step 3: scatter edges into CSR slots.
__global__ __launch_bounds__(256) void csr_fill(const int* __restrict__ ei,
                                                int* __restrict__ cursor,
                                                int* __restrict__ col)
{
    int i = blockIdx.x * 256 + threadIdx.x;
    if (i < NEDGE) {
        int dst  = ei[NEDGE + i];
        int slot = atomicAdd(&cursor[dst], 1);
        col[slot] = ei[i];
    }
}

// ---------------------------------------------------------------------------
// Gather-based segment mean: one wave per dst node, lane holds 2 dims.
__global__ __launch_bounds__(256) void gather_mean(
    const float* __restrict__ xsrc, const int* __restrict__ rowptr,
    const int* __restrict__ col, int N, float* __restrict__ out)
{
    int node = (blockIdx.x * 256 + threadIdx.x) >> 6;
    int lane = threadIdx.x & 63;
    if (node >= N) return;
    int s = rowptr[node], e = rowptr[node + 1];
    float2 acc; acc.x = 0.f; acc.y = 0.f;
    for (int j = s; j < e; j++) {
        int src = col[j];  // wave-uniform -> broadcast load
        float2 v = ((const float2*)(xsrc + (size_t)src * DIM))[lane];
        acc.x += v.x; acc.y += v.y;
    }
    float inv = (e > s) ? 1.f / (float)(e - s) : 0.f;
    acc.x *= inv; acc.y *= inv;
    ((float2*)(out + (size_t)node * DIM))[lane] = acc;
}

// ---------------------------------------------------------------------------
// Fused GEMM:  out[N][128] = concat(A-segments)[N][K] @ B[K][128] (+bias)
// Block = 256 threads, 32 rows per block, BK = 32.  In-place (out == A0) is
// safe: each block reads only its own 32 rows and writes them at the end.
__global__ __launch_bounds__(256) void gemm_fused(
    const float* __restrict__ A0,
    const float* __restrict__ A1,
    const float* __restrict__ A2,
    int N,
    const float* __restrict__ B, int K,
    const float* __restrict__ bias,
    float* __restrict__ out)
{
    __shared__ float As[32*33];
    __shared__ float Bs[32*132];

    int t    = threadIdx.x;
    int row0 = blockIdx.x * 32;
    int tc = t & 31, tr = t >> 5;

    float acc[4][4] = {};

    for (int kk = 0; kk < K; kk += 32) {
        int seg = kk >> 7, kl = kk & 127;
        const float* Ap = (seg==0) ? A0 : ((seg==1) ? A1 : A2);
        #pragma unroll
        for (int i = 0; i < 4; i++) {
            int s = t + i*256; int r = s >> 5, k = s & 31;
            int gr = row0 + r;
            As[r*33 + k] = (gr < N) ? Ap[(size_t)gr*DIM + kl + k] : 0.f;
        }
        #pragma unroll
        for (int i = 0; i < 4; i++) {
            int s = t + i*256; int k = s >> 5, j4 = s & 31;
            float4 v = *(const float4*)(B + (size_t)(kk + k)*DIM + j4*4);
            *(float4*)(&Bs[k*132 + j4*4]) = v;
        }
        __syncthreads();
        #pragma unroll
        for (int k = 0; k < 32; k++) {
            float4 b4 = *(const float4*)(&Bs[k*132 + tc*4]);
            #pragma unroll
            for (int i = 0; i < 4; i++) {
                float a = As[(tr*4 + i)*33 + k];
                acc[i][0] += a * b4.x;
                acc[i][1] += a * b4.y;
                acc[i][2] += a * b4.z;
                acc[i][3] += a * b4.w;
            }
        }
        __syncthreads();
    }

    #pragma unroll
    for (int i = 0; i < 4; i++) {
        int gr = row0 + tr*4 + i;
        if (gr < N) {
            float4 v;
            v.x = acc[i][0]; v.y = acc[i][1]; v.z = acc[i][2]; v.w = acc[i][3];
            if (bias) {
                v.x += bias[tc*4+0]; v.y += bias[tc*4+1];
                v.z += bias[tc*4+2]; v.w += bias[tc*4+3];
            }
            *(float4*)(out + (size_t)gr*DIM + tc*4) = v;
        }
    }
}

// ---------------------------------------------------------------------------
// LayerNorm + ReLU, one wave per row (2 floats/lane), width-64 shuffle reduce.
__global__ __launch_bounds__(256) void ln_relu(
    const float* __restrict__ src, float* __restrict__ dst, int N,
    const float* __restrict__ g, const float* __restrict__ b)
{
    int wid  = (blockIdx.x * 256 + threadIdx.x) >> 6;
    int lane = threadIdx.x & 63;
    if (wid >= N) return;
    float2 v = ((const float2*)(src + (size_t)wid * DIM))[lane];
    float s  = v.x + v.y;
    float sq = v.x*v.x + v.y*v.y;
    #pragma unroll
    for (int o = 32; o; o >>= 1) { s += __shfl_xor(s, o); sq += __shfl_xor(sq, o); }
    float m   = s * (1.f/128.f);
    float var = sq * (1.f/128.f) - m*m;
    float r   = rsqrtf(var + 1e-5f);
    float y0 = (v.x - m) * r * g[2*lane]   + b[2*lane];
    float y1 = (v.y - m) * r * g[2*lane+1] + b[2*lane+1];
    float2 o2; o2.x = fmaxf(y0, 0.f); o2.y = fmaxf(y1, 0.f);
    ((float2*)(dst + (size_t)wid * DIM))[lane] = o2;
}

// ---------------------------------------------------------------------------
// Head: out[N][16] = xp[N][128] @ Wh[128][16] + bh.  16 rows/block.
__global__ __launch_bounds__(256) void head_kernel(
    const float* __restrict__ xp, const float* __restrict__ Wh,
    const float* __restrict__ bh, float* __restrict__ out)
{
    __shared__ float Xs[16*128];
    __shared__ float Ws[128*16];
    int t = threadIdx.x;
    int row0 = blockIdx.x * 16;
    for (int i = t; i < 2048; i += 256) Ws[i] = Wh[i];
    #pragma unroll
    for (int i = 0; i < 8; i++) {
        int s = t + i*256; int r = s >> 7, k = s & 127;
        int gr = row0 + r;
        Xs[s] = (gr < NPAPER) ? xp[(size_t)gr*DIM + k] : 0.f;
    }
    __syncthreads();
    int r = t >> 4, c = t & 15;
    float acc = bh[c];
    #pragma unroll 16
    for (int k = 0; k < 128; k++) acc += Xs[r*128 + k] * Ws[k*16 + c];
    int gr = row0 + r;
    if (gr < NPAPER) out[(size_t)gr*NCLS + c] = acc;
}

// ---------------------------------------------------------------------------
extern "C" void kernel_launch(void* const* d_in, const int* in_sizes, int n_in,
                              void* d_out, int out_size, void* d_ws, size_t ws_size,
                              hipStream_t stream)
{
    const float* x_paper  = (const float*)d_in[0];
    const float* x_author = (const float*)d_in[1];
    const int*   ei_cites = (const int*)d_in[2];
    const int*   ei_writes= (const int*)d_in[3];
    const int*   ei_rev   = (const int*)d_in[4];
    const float* Wl       = (const float*)d_in[5];
    const float* Wr       = (const float*)d_in[6];
    const float* bl       = (const float*)d_in[7];
    const float* linp     = (const float*)d_in[8];
    const float* lina     = (const float*)d_in[9];
    const float* ln_s     = (const float*)d_in[10];
    const float* ln_b     = (const float*)d_in[11];
    const float* Wh       = (const float*)d_in[12];
    const float* bh       = (const float*)d_in[13];
    float* out = (float*)d_out;

    float* ws = (float*)d_ws;
    size_t off = 0;
    float* xp    = ws + off; off += (size_t)NPAPER * DIM;
    float* xa    = ws + off; off += (size_t)NAUTH  * DIM;
    float* aggC  = ws + off; off += (size_t)NPAPER * DIM;
    float* aggW  = ws + off; off += (size_t)NPAPER * DIM;
    float* aggR  = ws + off; off += (size_t)NAUTH  * DIM;
    float* Bp    = ws + off; off += 2*384*128;
    float* Ba    = ws + off; off += 2*256*128;
    float* LP    = ws + off; off += 128*128;
    float* LA    = ws + off; off += 128*128;
    float* biasp = ws + off; off += 2*128;
    float* biasa = ws + off; off += 2*128;
    int* iws = (int*)(ws + off);
    size_t ioff = 0;
    int* rowC = iws + ioff; ioff += NPAPER + 1;
    int* rowW = iws + ioff; ioff += NPAPER + 1;
    int* rowR = iws + ioff; ioff += NAUTH + 1;
    int* curC = iws + ioff; ioff += NPAPER;
    int* curW = iws + ioff; ioff += NPAPER;
    int* curR = iws + ioff; ioff += NAUTH;
    int* colC = iws + ioff; ioff += NEDGE;
    int* colW = iws + ioff; ioff += NEDGE;
    int* colR = iws + ioff; ioff += NEDGE;
    int* deg  = iws + ioff; ioff += NPAPER;
    int* bsum = iws + ioff; ioff += 256;

    prep_weights<<<(197120 + 255)/256, 256, 0, stream>>>(
        Wl, Wr, bl, linp, lina, Bp, Ba, LP, LA, biasp, biasa);

    // ---- CSR build (once per call; edges fixed across layers) ----
    const int* eis[3]  = { ei_cites, ei_writes, ei_rev };
    int*       rows[3] = { rowC, rowW, rowR };
    int*       curs[3] = { curC, curW, curR };
    int*       cols[3] = { colC, colW, colR };
    int        ns[3]   = { NPAPER, NPAPER, NAUTH };
    for (int tpe = 0; tpe < 3; tpe++) {
        int n  = ns[tpe];
        int nb = (n + 1023) / 1024;
        hipMemsetAsync(deg, 0, (size_t)n * 4, stream);
        deg_count<<<(NEDGE + 255)/256, 256, 0, stream>>>(eis[tpe], deg);
        scan_pass1<<<nb, 256, 0, stream>>>(deg, n, rows[tpe], bsum);
        scan_pass2<<<1, 256, 0, stream>>>(bsum, nb);
        scan_pass3<<<(n + 256)/256 + 1, 256, 0, stream>>>(rows[tpe], n, bsum, curs[tpe]);
        csr_fill<<<(NEDGE + 255)/256, 256, 0, stream>>>(eis[tpe], curs[tpe], cols[tpe]);
    }

    for (int l = 0; l < 2; l++) {
        const float* cur_p = (l == 0) ? x_paper  : xp;
        const float* cur_a = (l == 0) ? x_author : xa;

        gather_mean<<<NPAPER/4, 256, 0, stream>>>(cur_p, rowC, colC, NPAPER, aggC);
        gather_mean<<<NPAPER/4, 256, 0, stream>>>(cur_a, rowW, colW, NPAPER, aggW);
        gather_mean<<<NAUTH/4,  256, 0, stream>>>(cur_p, rowR, colR, NAUTH,  aggR);

        // paper: [meanC | meanW | x_p] (K=384) @ Bp[l]  -> aggC (in-place safe)
        gemm_fused<<<(NPAPER+31)/32, 256, 0, stream>>>(
            aggC, aggW, cur_p, NPAPER,
            Bp + (size_t)l*384*128, 384, biasp + l*128, aggC);
        // author: [meanR | x_a] (K=256) @ Ba[l] -> aggR
        gemm_fused<<<(NAUTH+31)/32, 256, 0, stream>>>(
            aggR, cur_a, nullptr, NAUTH,
            Ba + (size_t)l*256*128, 256, biasa + l*128, aggR);

        if (l == 0) {
            // residual: p = p @ (I + lin^T), in-place
            gemm_fused<<<(NPAPER+31)/32, 256, 0, stream>>>(
                aggC, nullptr, nullptr, NPAPER, LP, 128, nullptr, aggC);
            gemm_fused<<<(NAUTH+31)/32, 256, 0, stream>>>(
                aggR, nullptr, nullptr, NAUTH, LA, 128, nullptr, aggR);
        }

        ln_relu<<<NPAPER/4, 256, 0, stream>>>(aggC, xp, NPAPER,
                                              ln_s + (l*2+0)*128, ln_b + (l*2+0)*128);
        ln_relu<<<NAUTH/4, 256, 0, stream>>>(aggR, xa, NAUTH,
                                             ln_s + (l*2+1)*128, ln_b + (l*2+1)*128);
    }

    head_kernel<<<(NPAPER+15)/16, 256, 0, stream>>>(xp, Wh, bh, out);
}

// Round 3
// 601.759 us; speedup vs baseline: 5.5331x; 2.1403x over previous
//
#include <hip/hip_runtime.h>
#include <math.h>

#define NPAPER 100000
#define NAUTH  50000
#define DIM    128
#define NEDGE  500000
#define NCLS   16

typedef unsigned int   uint;
typedef unsigned short ushort;
using short8 = __attribute__((ext_vector_type(8))) short;
using f32x4  = __attribute__((ext_vector_type(4))) float;

__device__ __forceinline__ float b2f(uint u) {
    return __uint_as_float(u << 16);
}
__device__ __forceinline__ ushort f2b(float f) {   // round-to-nearest-even
    uint x = __float_as_uint(f);
    return (ushort)((x + 0x7fffu + ((x >> 16) & 1u)) >> 16);
}

// ---------------------------------------------------------------------------
// prep 1: Bp[l]: [384][128] k-major f32 = [Wl0^T; Wl1^T; (Wr0+Wr1)^T]
//         Ba[l]: [256][128] = [Wl2^T; Wr2^T];  biasp/biasa
__global__ __launch_bounds__(256) void prep_weights(
    const float* __restrict__ Wl, const float* __restrict__ Wr,
    const float* __restrict__ bl,
    float* __restrict__ Bp, float* __restrict__ Ba,
    float* __restrict__ biasp, float* __restrict__ biasa)
{
    int t = blockIdx.x * 256 + threadIdx.x;
    if (t < 2*384*128) {
        int l = t / (384*128); int rem = t - l*(384*128);
        int k = rem >> 7, j = rem & 127;
        float v;
        if (k < 128)      v = Wl[((l*3+0)*128 + j)*128 + k];
        else if (k < 256) v = Wl[((l*3+1)*128 + j)*128 + (k-128)];
        else              v = Wr[((l*3+0)*128 + j)*128 + (k-256)]
                            + Wr[((l*3+1)*128 + j)*128 + (k-256)];
        Bp[t] = v;
        return;
    }
    t -= 2*384*128;
    if (t < 2*256*128) {
        int l = t / (256*128); int rem = t - l*(256*128);
        int k = rem >> 7, j = rem & 127;
        Ba[t] = (k < 128) ? Wl[((l*3+2)*128 + j)*128 + k]
                          : Wr[((l*3+2)*128 + j)*128 + (k-128)];
        return;
    }
    t -= 2*256*128;
    if (t < 256) { int l=t>>7, j=t&127; biasp[t] = bl[(l*3+0)*128+j] + bl[(l*3+1)*128+j]; return; }
    t -= 256;
    if (t < 256) { int l=t>>7, j=t&127; biasa[t] = bl[(l*3+2)*128+j]; return; }
}

// prep 2: residual fold + transpose + bf16.
// Btp[l][j][k] = bf16( Bp[l][k][j] + (l==0 ? sum_m Bp[l][k][m]*linp[j][m] : 0) )
__global__ __launch_bounds__(256) void build_bt(
    const float* __restrict__ Bp, const float* __restrict__ Ba,
    const float* __restrict__ linp, const float* __restrict__ lina,
    ushort* __restrict__ Btp, ushort* __restrict__ Bta)
{
    int t = blockIdx.x * 256 + threadIdx.x;
    if (t < 2*128*384) {
        int l = t / (128*384); int rem = t - l*(128*384);
        int j = rem / 384, k = rem - j*384;
        const float* brow = Bp + (size_t)l*384*128 + (size_t)k*128;
        float v = brow[j];
        if (l == 0) {
            const float* lrow = linp + (size_t)j*128;
            float s = 0.f;
            #pragma unroll 8
            for (int m = 0; m < 128; m++) s += brow[m] * lrow[m];
            v += s;
        }
        Btp[t] = f2b(v);
        return;
    }
    t -= 2*128*384;
    if (t < 2*128*256) {
        int l = t / (128*256); int rem = t - l*(128*256);
        int j = rem / 256, k = rem - j*256;
        const float* brow = Ba + (size_t)l*256*128 + (size_t)k*128;
        float v = brow[j];
        if (l == 0) {
            const float* lrow = lina + (size_t)j*128;
            float s = 0.f;
            #pragma unroll 8
            for (int m = 0; m < 128; m++) s += brow[m] * lrow[m];
            v += s;
        }
        Bta[t] = f2b(v);
    }
}

// prep 3: bias' = bias @ (I + lin^T) for l=0 (pass-through l=1)
__global__ __launch_bounds__(256) void fold_bias(
    const float* __restrict__ biasp, const float* __restrict__ biasa,
    const float* __restrict__ linp, const float* __restrict__ lina,
    float* __restrict__ biasp2, float* __restrict__ biasa2)
{
    int t = blockIdx.x * 256 + threadIdx.x;   // 512 total
    if (t < 512) {
        int isa = t >> 8; int r = t & 255;
        int l = r >> 7, j = r & 127;
        const float* bsrc = isa ? biasa : biasp;
        const float* lin  = isa ? lina  : linp;
        float v = bsrc[r];
        if (l == 0) {
            float s = 0.f;
            for (int k = 0; k < 128; k++) s += bsrc[k] * lin[j*128 + k];
            v += s;
        }
        (isa ? biasa2 : biasp2)[r] = v;
    }
}

// ---------------------------------------------------------------------------
// fp32 -> bf16 conversion, 4 elems/thread.
__global__ __launch_bounds__(256) void to_bf16(const float* __restrict__ x,
                                               ushort* __restrict__ y, int n4)
{
    int i = blockIdx.x * 256 + threadIdx.x;
    if (i >= n4) return;
    float4 v = ((const float4*)x)[i];
    uint2 o;
    o.x = (uint)f2b(v.x) | ((uint)f2b(v.y) << 16);
    o.y = (uint)f2b(v.z) | ((uint)f2b(v.w) << 16);
    ((uint2*)y)[i] = o;
}

// ---------------------------------------------------------------------------
// CSR build (unchanged).
__global__ __launch_bounds__(256) void deg_count(const int* __restrict__ ei,
                                                 int* __restrict__ deg)
{
    int i = blockIdx.x * 256 + threadIdx.x;
    if (i < NEDGE) atomicAdd(&deg[ei[NEDGE + i]], 1);
}

__global__ __launch_bounds__(256) void scan_pass1(const int* __restrict__ in, int n,
                                                  int* __restrict__ out,
                                                  int* __restrict__ bsum)
{
    __shared__ int lds[256];
    int b0 = blockIdx.x * 1024;
    int t  = threadIdx.x;
    int v[4]; int s = 0;
    #pragma unroll
    for (int i = 0; i < 4; i++) {
        int idx = b0 + t*4 + i;
        v[i] = (idx < n) ? in[idx] : 0;
        s += v[i];
    }
    lds[t] = s;
    __syncthreads();
    for (int o = 1; o < 256; o <<= 1) {
        int x = (t >= o) ? lds[t - o] : 0;
        __syncthreads();
        lds[t] += x;
        __syncthreads();
    }
    int run = (t > 0) ? lds[t-1] : 0;
    if (t == 255) bsum[blockIdx.x] = lds[255];
    #pragma unroll
    for (int i = 0; i < 4; i++) {
        int idx = b0 + t*4 + i;
        if (idx < n) out[idx] = run;
        run += v[i];
    }
}

__global__ __launch_bounds__(256) void scan_pass2(int* __restrict__ bsum, int nb)
{
    __shared__ int lds[256];
    int t = threadIdx.x;
    lds[t] = (t < nb) ? bsum[t] : 0;
    __syncthreads();
    for (int o = 1; o < 256; o <<= 1) {
        int x = (t >= o) ? lds[t - o] : 0;
        __syncthreads();
        lds[t] += x;
        __syncthreads();
    }
    if (t < nb) bsum[t] = (t > 0) ? lds[t-1] : 0;
}

__global__ __launch_bounds__(256) void scan_pass3(int* __restrict__ out, int n,
                                                  const int* __restrict__ bsum,
                                                  int* __restrict__ cursor)
{
    int i = blockIdx.x * 256 + threadIdx.x;
    if (i < n) {
        int v = out[i] + bsum[i >> 10];
        out[i] = v;
        cursor[i] = v;
    }
    if (i == n) out[n] = NEDGE;
}

__global__ __launch_bounds__(256) void csr_fill(const int* __restrict__ ei,
                                                int* __restrict__ cursor,
                                                int* __restrict__ col)
{
    int i = blockIdx.x * 256 + threadIdx.x;
    if (i < NEDGE) {
        int dst  = ei[NEDGE + i];
        int slot = atomicAdd(&cursor[dst], 1);
        col[slot] = ei[i];
    }
}

// ---------------------------------------------------------------------------
// Gather mean, bf16 in/out: half-wave (32 lanes) per node, 4 bf16 per lane.
__global__ __launch_bounds__(256) void gather_mean_b(
    const ushort* __restrict__ xsrc, const int* __restrict__ rowptr,
    const int* __restrict__ col, int N, ushort* __restrict__ out)
{
    int node = (blockIdx.x * 256 + threadIdx.x) >> 5;
    int lane = threadIdx.x & 31;
    if (node >= N) return;
    int s = rowptr[node], e = rowptr[node + 1];
    float a0 = 0.f, a1 = 0.f, a2 = 0.f, a3 = 0.f;
    for (int j = s; j < e; j++) {
        int src = col[j];
        uint2 v = *(const uint2*)(xsrc + (size_t)src * DIM + lane * 4);
        a0 += b2f(v.x & 0xffffu); a1 += b2f(v.x >> 16);
        a2 += b2f(v.y & 0xffffu); a3 += b2f(v.y >> 16);
    }
    float inv = (e > s) ? 1.f / (float)(e - s) : 0.f;
    uint2 o;
    o.x = (uint)f2b(a0 * inv) | ((uint)f2b(a1 * inv) << 16);
    o.y = (uint)f2b(a2 * inv) | ((uint)f2b(a3 * inv) << 16);
    *(uint2*)(out + (size_t)node * DIM + lane * 4) = o;
}

// ---------------------------------------------------------------------------
// MFMA GEMM + fused bias + LayerNorm + ReLU, bf16 in / bf16 out.
//   out[r][:] = relu(LN( concat(A0|A1|A2)[r][:] @ Bt^T + bias ))
// Bt is [128][K] (output-col major).  Block: 256 thr (4 waves), 64 rows,
// full N=128.  Wave w owns rows w*16..w*16+16 -> per-row LN is wave-local.
__global__ __launch_bounds__(256) void gemm_ln(
    const ushort* __restrict__ A0, const ushort* __restrict__ A1,
    const ushort* __restrict__ A2, int N,
    const ushort* __restrict__ Bt, int K,
    const float* __restrict__ bias,
    const float* __restrict__ lng, const float* __restrict__ lnb,
    ushort* __restrict__ out)
{
    constexpr int ASTR = 72, BSTR = 72;   // +8 bf16 pad: banks spread, 16B aligned
    __shared__ ushort As[64 * ASTR];
    __shared__ ushort Bs[128 * BSTR];

    int t    = threadIdx.x;
    int w    = t >> 6;
    int lane = t & 63;
    int row0 = blockIdx.x * 64;
    int l15  = lane & 15;
    int g4   = lane >> 4;

    f32x4 acc[8];
    #pragma unroll
    for (int f = 0; f < 8; f++) acc[f] = (f32x4){0.f, 0.f, 0.f, 0.f};

    for (int kk = 0; kk < K; kk += 64) {
        int seg = kk >> 7, kl = kk & 127;
        const ushort* Ap = (seg == 0) ? A0 : ((seg == 1) ? A1 : A2);
        // stage A tile: 64 rows x 64 k  (512 x 8-short chunks, 2 passes)
        #pragma unroll
        for (int p = 0; p < 2; p++) {
            int idx = t + p*256;
            int r = idx >> 3, kc = (idx & 7) * 8;
            int gr = row0 + r;
            uint4 v = (gr < N) ? *(const uint4*)(Ap + (size_t)gr*DIM + kl + kc)
                               : (uint4){0,0,0,0};
            *(uint4*)(&As[r*ASTR + kc]) = v;
        }
        // stage B tile: 128 cols x 64 k  (1024 chunks, 4 passes)
        #pragma unroll
        for (int p = 0; p < 4; p++) {
            int idx = t + p*256;
            int j = idx >> 3, kc = (idx & 7) * 8;
            uint4 v = *(const uint4*)(Bt + (size_t)j*K + kk + kc);
            *(uint4*)(&Bs[j*BSTR + kc]) = v;
        }
        __syncthreads();
        #pragma unroll
        for (int ks = 0; ks < 2; ks++) {
            short8 av = *(const short8*)(&As[(w*16 + l15)*ASTR + ks*32 + g4*8]);
            #pragma unroll
            for (int f = 0; f < 8; f++) {
                short8 bv = *(const short8*)(&Bs[(f*16 + l15)*BSTR + ks*32 + g4*8]);
                acc[f] = __builtin_amdgcn_mfma_f32_16x16x32_bf16(av, bv, acc[f], 0, 0, 0);
            }
        }
        __syncthreads();
    }

    // epilogue: bias + LN + ReLU + bf16 store.  lane holds rows g4*4+i, col f*16+l15.
    float bv[8], gv[8], bbv[8];
    #pragma unroll
    for (int f = 0; f < 8; f++) {
        bv[f]  = bias[f*16 + l15];
        gv[f]  = lng [f*16 + l15];
        bbv[f] = lnb [f*16 + l15];
    }
    #pragma unroll
    for (int i = 0; i < 4; i++) {
        int grow = row0 + w*16 + g4*4 + i;
        float vv[8];
        float s = 0.f, sq = 0.f;
        #pragma unroll
        for (int f = 0; f < 8; f++) {
            vv[f] = acc[f][i] + bv[f];
            s  += vv[f];
            sq += vv[f] * vv[f];
        }
        s  += __shfl_xor(s, 1);  sq += __shfl_xor(sq, 1);
        s  += __shfl_xor(s, 2);  sq += __shfl_xor(sq, 2);
        s  += __shfl_xor(s, 4);  sq += __shfl_xor(sq, 4);
        s  += __shfl_xor(s, 8);  sq += __shfl_xor(sq, 8);
        float m   = s * (1.f/128.f);
        float var = sq * (1.f/128.f) - m*m;
        float rr  = rsqrtf(var + 1e-5f);
        if (grow < N) {
            #pragma unroll
            for (int f = 0; f < 8; f++) {
                float y = (vv[f] - m) * rr * gv[f] + bbv[f];
                y = fmaxf(y, 0.f);
                out[(size_t)grow*DIM + f*16 + l15] = f2b(y);
            }
        }
    }
}

// ---------------------------------------------------------------------------
// Head: out[N][16] = xp(bf16)[N][128] @ Wh[128][16] + bh.  16 rows/block.
__global__ __launch_bounds__(256) void head_kernel(
    const ushort* __restrict__ xp, const float* __restrict__ Wh,
    const float* __restrict__ bh, float* __restrict__ out)
{
    __shared__ float Xs[16*128];
    __shared__ float Ws[128*16];
    int t = threadIdx.x;
    int row0 = blockIdx.x * 16;
    for (int i = t; i < 2048; i += 256) Ws[i] = Wh[i];
    {
        int r = t >> 4, k8 = (t & 15) * 8;
        int gr = row0 + r;
        if (gr < NPAPER) {
            uint4 v = *(const uint4*)(xp + (size_t)gr*DIM + k8);
            const ushort* pv = (const ushort*)&v;
            #pragma unroll
            for (int i = 0; i < 8; i++) Xs[r*128 + k8 + i] = b2f(pv[i]);
        } else {
            #pragma unroll
            for (int i = 0; i < 8; i++) Xs[r*128 + k8 + i] = 0.f;
        }
    }
    __syncthreads();
    int r = t >> 4, c = t & 15;
    float acc = bh[c];
    #pragma unroll 16
    for (int k = 0; k < 128; k++) acc += Xs[r*128 + k] * Ws[k*16 + c];
    int gr = row0 + r;
    if (gr < NPAPER) out[(size_t)gr*NCLS + c] = acc;
}

// ---------------------------------------------------------------------------
extern "C" void kernel_launch(void* const* d_in, const int* in_sizes, int n_in,
                              void* d_out, int out_size, void* d_ws, size_t ws_size,
                              hipStream_t stream)
{
    const float* x_paper  = (const float*)d_in[0];
    const float* x_author = (const float*)d_in[1];
    const int*   ei_cites = (const int*)d_in[2];
    const int*   ei_writes= (const int*)d_in[3];
    const int*   ei_rev   = (const int*)d_in[4];
    const float* Wl       = (const float*)d_in[5];
    const float* Wr       = (const float*)d_in[6];
    const float* bl       = (const float*)d_in[7];
    const float* linp     = (const float*)d_in[8];
    const float* lina     = (const float*)d_in[9];
    const float* ln_s     = (const float*)d_in[10];
    const float* ln_b     = (const float*)d_in[11];
    const float* Wh       = (const float*)d_in[12];
    const float* bh       = (const float*)d_in[13];
    float* out = (float*)d_out;

    float* ws = (float*)d_ws;
    size_t off = 0;
    float* Bp     = ws + off; off += 2*384*128;
    float* Ba     = ws + off; off += 2*256*128;
    float* biasp  = ws + off; off += 2*128;
    float* biasa  = ws + off; off += 2*128;
    float* biasp2 = ws + off; off += 2*128;
    float* biasa2 = ws + off; off += 2*128;

    ushort* uws = (ushort*)(ws + off);
    size_t uoff = 0;
    ushort* xpb0 = uws + uoff; uoff += (size_t)NPAPER * DIM;
    ushort* xab0 = uws + uoff; uoff += (size_t)NAUTH  * DIM;
    ushort* xpb1 = uws + uoff; uoff += (size_t)NPAPER * DIM;
    ushort* xab1 = uws + uoff; uoff += (size_t)NAUTH  * DIM;
    ushort* aggC = uws + uoff; uoff += (size_t)NPAPER * DIM;
    ushort* aggW = uws + uoff; uoff += (size_t)NPAPER * DIM;
    ushort* aggR = uws + uoff; uoff += (size_t)NAUTH  * DIM;
    ushort* Btp  = uws + uoff; uoff += 2*128*384;
    ushort* Bta  = uws + uoff; uoff += 2*128*256;
    if (uoff & 1) uoff++;

    int* iws = (int*)(uws + uoff);
    size_t ioff = 0;
    int* rowC = iws + ioff; ioff += NPAPER + 1;
    int* rowW = iws + ioff; ioff += NPAPER + 1;
    int* rowR = iws + ioff; ioff += NAUTH + 1;
    int* curC = iws + ioff; ioff += NPAPER;
    int* curW = iws + ioff; ioff += NPAPER;
    int* curR = iws + ioff; ioff += NAUTH;
    int* colC = iws + ioff; ioff += NEDGE;
    int* colW = iws + ioff; ioff += NEDGE;
    int* colR = iws + ioff; ioff += NEDGE;
    int* deg  = iws + ioff; ioff += NPAPER;
    int* bsum = iws + ioff; ioff += 256;

    // ---- weight prep ----
    prep_weights<<<(2*384*128 + 2*256*128 + 512 + 255)/256, 256, 0, stream>>>(
        Wl, Wr, bl, Bp, Ba, biasp, biasa);
    build_bt<<<(2*128*384 + 2*128*256 + 255)/256, 256, 0, stream>>>(
        Bp, Ba, linp, lina, Btp, Bta);
    fold_bias<<<2, 256, 0, stream>>>(biasp, biasa, linp, lina, biasp2, biasa2);

    // ---- input conversion to bf16 ----
    to_bf16<<<(NPAPER*DIM/4 + 255)/256, 256, 0, stream>>>(x_paper,  xpb0, NPAPER*DIM/4);
    to_bf16<<<(NAUTH*DIM/4 + 255)/256, 256, 0, stream>>>(x_author, xab0, NAUTH*DIM/4);

    // ---- CSR build ----
    const int* eis[3]  = { ei_cites, ei_writes, ei_rev };
    int*       rows[3] = { rowC, rowW, rowR };
    int*       curs[3] = { curC, curW, curR };
    int*       cols[3] = { colC, colW, colR };
    int        ns[3]   = { NPAPER, NPAPER, NAUTH };
    for (int tpe = 0; tpe < 3; tpe++) {
        int n  = ns[tpe];
        int nb = (n + 1023) / 1024;
        hipMemsetAsync(deg, 0, (size_t)n * 4, stream);
        deg_count<<<(NEDGE + 255)/256, 256, 0, stream>>>(eis[tpe], deg);
        scan_pass1<<<nb, 256, 0, stream>>>(deg, n, rows[tpe], bsum);
        scan_pass2<<<1, 256, 0, stream>>>(bsum, nb);
        scan_pass3<<<(n + 256)/256 + 1, 256, 0, stream>>>(rows[tpe], n, bsum, curs[tpe]);
        csr_fill<<<(NEDGE + 255)/256, 256, 0, stream>>>(eis[tpe], curs[tpe], cols[tpe]);
    }

    // ---- 2 layers ----
    for (int l = 0; l < 2; l++) {
        const ushort* cur_p = (l == 0) ? xpb0 : xpb1;
        const ushort* cur_a = (l == 0) ? xab0 : xab1;

        gather_mean_b<<<NPAPER*32/256, 256, 0, stream>>>(cur_p, rowC, colC, NPAPER, aggC);
        gather_mean_b<<<NPAPER*32/256, 256, 0, stream>>>(cur_a, rowW, colW, NPAPER, aggW);
        gather_mean_b<<<NAUTH*32/256,  256, 0, stream>>>(cur_p, rowR, colR, NAUTH,  aggR);

        // paper: [meanC | meanW | x_p] (K=384) @ Btp[l]^T, +bias, LN, ReLU -> xpb1
        gemm_ln<<<(NPAPER + 63)/64, 256, 0, stream>>>(
            aggC, aggW, cur_p, NPAPER,
            Btp + (size_t)l*128*384, 384, biasp2 + l*128,
            ln_s + (l*2+0)*128, ln_b + (l*2+0)*128, xpb1);
        // author: [meanR | x_a] (K=256) @ Bta[l]^T -> xab1
        gemm_ln<<<(NAUTH + 63)/64, 256, 0, stream>>>(
            aggR, cur_a, nullptr, NAUTH,
            Bta + (size_t)l*128*256, 256, biasa2 + l*128,
            ln_s + (l*2+1)*128, ln_b + (l*2+1)*128, xab1);
    }

    head_kernel<<<(NPAPER + 15)/16, 256, 0, stream>>>(xpb1, Wh, bh, out);
}

// Round 4
// 468.772 us; speedup vs baseline: 7.1028x; 1.2837x over previous
//
#include <hip/hip_runtime.h>
#include <math.h>

#define NPAPER 100000
#define NAUTH  50000
#define DIM    128
#define NEDGE  500000
#define NCLS   16

typedef unsigned int   uint;
typedef unsigned short ushort;
using short8 = __attribute__((ext_vector_type(8))) short;
using f32x4  = __attribute__((ext_vector_type(4))) float;

__device__ __forceinline__ float b2f(uint u) {
    return __uint_as_float(u << 16);
}
__device__ __forceinline__ ushort f2b(float f) {   // round-to-nearest-even
    uint x = __float_as_uint(f);
    return (ushort)((x + 0x7fffu + ((x >> 16) & 1u)) >> 16);
}

// global_load_lds: linear LDS dest (wave base + lane*16), per-lane global src.
#define GLD_LDS16(srcp, ldsp) \
    __builtin_amdgcn_global_load_lds( \
        (const __attribute__((address_space(1))) void*)(srcp), \
        (__attribute__((address_space(3))) void*)(ldsp), 16, 0, 0)

// ---------------------------------------------------------------------------
// prep 1: Bp[l]: [384][128] k-major f32 = [Wl0^T; Wl1^T; (Wr0+Wr1)^T]
//         Ba[l]: [256][128] = [Wl2^T; Wr2^T];  biasp/biasa
__global__ __launch_bounds__(256) void prep_weights(
    const float* __restrict__ Wl, const float* __restrict__ Wr,
    const float* __restrict__ bl,
    float* __restrict__ Bp, float* __restrict__ Ba,
    float* __restrict__ biasp, float* __restrict__ biasa)
{
    int t = blockIdx.x * 256 + threadIdx.x;
    if (t < 2*384*128) {
        int l = t / (384*128); int rem = t - l*(384*128);
        int k = rem >> 7, j = rem & 127;
        float v;
        if (k < 128)      v = Wl[((l*3+0)*128 + j)*128 + k];
        else if (k < 256) v = Wl[((l*3+1)*128 + j)*128 + (k-128)];
        else              v = Wr[((l*3+0)*128 + j)*128 + (k-256)]
                            + Wr[((l*3+1)*128 + j)*128 + (k-256)];
        Bp[t] = v;
        return;
    }
    t -= 2*384*128;
    if (t < 2*256*128) {
        int l = t / (256*128); int rem = t - l*(256*128);
        int k = rem >> 7, j = rem & 127;
        Ba[t] = (k < 128) ? Wl[((l*3+2)*128 + j)*128 + k]
                          : Wr[((l*3+2)*128 + j)*128 + (k-128)];
        return;
    }
    t -= 2*256*128;
    if (t < 256) { int l=t>>7, j=t&127; biasp[t] = bl[(l*3+0)*128+j] + bl[(l*3+1)*128+j]; return; }
    t -= 256;
    if (t < 256) { int l=t>>7, j=t&127; biasa[t] = bl[(l*3+2)*128+j]; return; }
}

// prep 2: residual fold + bf16 + PACK into MFMA-fragment order.
// Per 64-k step: [ks(2)][f(8)][lane(64)][8 elems], elem (col j = f*16+(lane&15),
// k = kk + ks*32 + (lane>>4)*8 + jj).  Staging then = pure linear copy.
__device__ __forceinline__ size_t pack_off(int j, int k) {
    int kstep = k >> 6, ks = (k >> 5) & 1, g4 = (k >> 3) & 3, jj = k & 7;
    int f = j >> 4, l15 = j & 15;
    return (size_t)kstep*8192 + (size_t)(ks*512 + f*64 + g4*16 + l15)*8 + jj;
}

__global__ __launch_bounds__(256) void build_bt(
    const float* __restrict__ Bp, const float* __restrict__ Ba,
    const float* __restrict__ linp, const float* __restrict__ lina,
    ushort* __restrict__ Btp, ushort* __restrict__ Bta)
{
    int t = blockIdx.x * 256 + threadIdx.x;
    if (t < 2*128*384) {
        int l = t / (128*384); int rem = t - l*(128*384);
        int j = rem / 384, k = rem - j*384;
        const float* brow = Bp + (size_t)l*384*128 + (size_t)k*128;
        float v = brow[j];
        if (l == 0) {
            const float* lrow = linp + (size_t)j*128;
            float s = 0.f;
            #pragma unroll 8
            for (int m = 0; m < 128; m++) s += brow[m] * lrow[m];
            v += s;
        }
        Btp[(size_t)l*49152 + pack_off(j, k)] = f2b(v);
        return;
    }
    t -= 2*128*384;
    if (t < 2*128*256) {
        int l = t / (128*256); int rem = t - l*(128*256);
        int j = rem / 256, k = rem - j*256;
        const float* brow = Ba + (size_t)l*256*128 + (size_t)k*128;
        float v = brow[j];
        if (l == 0) {
            const float* lrow = lina + (size_t)j*128;
            float s = 0.f;
            #pragma unroll 8
            for (int m = 0; m < 128; m++) s += brow[m] * lrow[m];
            v += s;
        }
        Bta[(size_t)l*32768 + pack_off(j, k)] = f2b(v);
    }
}

// prep 3: bias' = bias @ (I + lin^T) for l=0 (pass-through l=1)
__global__ __launch_bounds__(256) void fold_bias(
    const float* __restrict__ biasp, const float* __restrict__ biasa,
    const float* __restrict__ linp, const float* __restrict__ lina,
    float* __restrict__ biasp2, float* __restrict__ biasa2)
{
    int t = blockIdx.x * 256 + threadIdx.x;   // 512 total
    if (t < 512) {
        int isa = t >> 8; int r = t & 255;
        int l = r >> 7, j = r & 127;
        const float* bsrc = isa ? biasa : biasp;
        const float* lin  = isa ? lina  : linp;
        float v = bsrc[r];
        if (l == 0) {
            float s = 0.f;
            for (int k = 0; k < 128; k++) s += bsrc[k] * lin[j*128 + k];
            v += s;
        }
        (isa ? biasa2 : biasp2)[r] = v;
    }
}

// ---------------------------------------------------------------------------
// fp32 -> bf16 conversion, 4 elems/thread.
__global__ __launch_bounds__(256) void to_bf16(const float* __restrict__ x,
                                               ushort* __restrict__ y, int n4)
{
    int i = blockIdx.x * 256 + threadIdx.x;
    if (i >= n4) return;
    float4 v = ((const float4*)x)[i];
    uint2 o;
    o.x = (uint)f2b(v.x) | ((uint)f2b(v.y) << 16);
    o.y = (uint)f2b(v.z) | ((uint)f2b(v.w) << 16);
    ((uint2*)y)[i] = o;
}

// ---------------------------------------------------------------------------
// CSR build (unchanged).
__global__ __launch_bounds__(256) void deg_count(const int* __restrict__ ei,
                                                 int* __restrict__ deg)
{
    int i = blockIdx.x * 256 + threadIdx.x;
    if (i < NEDGE) atomicAdd(&deg[ei[NEDGE + i]], 1);
}

__global__ __launch_bounds__(256) void scan_pass1(const int* __restrict__ in, int n,
                                                  int* __restrict__ out,
                                                  int* __restrict__ bsum)
{
    __shared__ int lds[256];
    int b0 = blockIdx.x * 1024;
    int t  = threadIdx.x;
    int v[4]; int s = 0;
    #pragma unroll
    for (int i = 0; i < 4; i++) {
        int idx = b0 + t*4 + i;
        v[i] = (idx < n) ? in[idx] : 0;
        s += v[i];
    }
    lds[t] = s;
    __syncthreads();
    for (int o = 1; o < 256; o <<= 1) {
        int x = (t >= o) ? lds[t - o] : 0;
        __syncthreads();
        lds[t] += x;
        __syncthreads();
    }
    int run = (t > 0) ? lds[t-1] : 0;
    if (t == 255) bsum[blockIdx.x] = lds[255];
    #pragma unroll
    for (int i = 0; i < 4; i++) {
        int idx = b0 + t*4 + i;
        if (idx < n) out[idx] = run;
        run += v[i];
    }
}

__global__ __launch_bounds__(256) void scan_pass2(int* __restrict__ bsum, int nb)
{
    __shared__ int lds[256];
    int t = threadIdx.x;
    lds[t] = (t < nb) ? bsum[t] : 0;
    __syncthreads();
    for (int o = 1; o < 256; o <<= 1) {
        int x = (t >= o) ? lds[t - o] : 0;
        __syncthreads();
        lds[t] += x;
        __syncthreads();
    }
    if (t < nb) bsum[t] = (t > 0) ? lds[t-1] : 0;
}

__global__ __launch_bounds__(256) void scan_pass3(int* __restrict__ out, int n,
                                                  const int* __restrict__ bsum,
                                                  int* __restrict__ cursor)
{
    int i = blockIdx.x * 256 + threadIdx.x;
    if (i < n) {
        int v = out[i] + bsum[i >> 10];
        out[i] = v;
        cursor[i] = v;
    }
    if (i == n) out[n] = NEDGE;
}

__global__ __launch_bounds__(256) void csr_fill(const int* __restrict__ ei,
                                                int* __restrict__ cursor,
                                                int* __restrict__ col)
{
    int i = blockIdx.x * 256 + threadIdx.x;
    if (i < NEDGE) {
        int dst  = ei[NEDGE + i];
        int slot = atomicAdd(&cursor[dst], 1);
        col[slot] = ei[i];
    }
}

// ---------------------------------------------------------------------------
// Fused gather of all 3 edge types of a layer.  16 lanes per node, uint4 row
// chunks (16 B/lane), j-loop unrolled x2 with dual accumulators.
__device__ __forceinline__ void acc8(float* a, uint4 v) {
    a[0] += b2f(v.x & 0xffffu); a[1] += b2f(v.x >> 16);
    a[2] += b2f(v.y & 0xffffu); a[3] += b2f(v.y >> 16);
    a[4] += b2f(v.z & 0xffffu); a[5] += b2f(v.z >> 16);
    a[6] += b2f(v.w & 0xffffu); a[7] += b2f(v.w >> 16);
}

__global__ __launch_bounds__(256) void gather3(
    const ushort* __restrict__ xp, const ushort* __restrict__ xa,
    const int* __restrict__ rowC, const int* __restrict__ colC,
    const int* __restrict__ rowW, const int* __restrict__ colW,
    const int* __restrict__ rowR, const int* __restrict__ colR,
    ushort* __restrict__ aggC, ushort* __restrict__ aggW,
    ushort* __restrict__ aggR)
{
    int g    = (blockIdx.x * 256 + threadIdx.x) >> 4;
    int lane = threadIdx.x & 15;
    const ushort* xs; const int* rp; const int* cl; ushort* out; int node;
    if (g < NPAPER)            { node = g;            xs = xp; rp = rowC; cl = colC; out = aggC; }
    else if (g < 2*NPAPER)     { node = g -   NPAPER; xs = xa; rp = rowW; cl = colW; out = aggW; }
    else                       { node = g - 2*NPAPER; xs = xp; rp = rowR; cl = colR; out = aggR; }

    int s = rp[node], e = rp[node + 1];
    float a[8] = {0,0,0,0,0,0,0,0};
    float b[8] = {0,0,0,0,0,0,0,0};
    int j = s;
    for (; j + 2 <= e; j += 2) {
        int s0 = cl[j], s1 = cl[j+1];
        uint4 v0 = *(const uint4*)(xs + (size_t)s0 * DIM + lane * 8);
        uint4 v1 = *(const uint4*)(xs + (size_t)s1 * DIM + lane * 8);
        acc8(a, v0);
        acc8(b, v1);
    }
    if (j < e) {
        uint4 v0 = *(const uint4*)(xs + (size_t)cl[j] * DIM + lane * 8);
        acc8(a, v0);
    }
    float inv = (e > s) ? 1.f / (float)(e - s) : 0.f;
    #pragma unroll
    for (int i = 0; i < 8; i++) a[i] = (a[i] + b[i]) * inv;
    uint4 o;
    o.x = (uint)f2b(a[0]) | ((uint)f2b(a[1]) << 16);
    o.y = (uint)f2b(a[2]) | ((uint)f2b(a[3]) << 16);
    o.z = (uint)f2b(a[4]) | ((uint)f2b(a[5]) << 16);
    o.w = (uint)f2b(a[6]) | ((uint)f2b(a[7]) << 16);
    *(uint4*)(out + (size_t)node * DIM + lane * 8) = o;
}

// ---------------------------------------------------------------------------
// MFMA GEMM + fused bias + LayerNorm + ReLU, bf16 in / bf16 out.
// Block: 256 thr (4 waves), 128 rows (wave owns 32), full N=128, K-step 64.
// LDS layout (fragment-contiguous, zero bank conflicts):
//   As: [ks(2)][rb(8)][lane(64)][16B]  staged via global_load_lds with
//       per-lane-swizzled global source (A stays row-major in global).
//   Bs: [ks(2)][f(8)][lane(64)][16B]   staged linearly from pre-packed Bt.
// Frag reads are ds_read_b128 at base+lane*16 -> conflict-free.
__global__ __launch_bounds__(256) void gemm_ln(
    const ushort* __restrict__ A0, const ushort* __restrict__ A1,
    const ushort* __restrict__ A2, int N,
    const ushort* __restrict__ Bt, int K,
    const float* __restrict__ bias,
    const float* __restrict__ lng, const float* __restrict__ lnb,
    ushort* __restrict__ out)
{
    __shared__ ushort As[8192];   // 16 KB
    __shared__ ushort Bs[8192];   // 16 KB

    int t    = threadIdx.x;
    int w    = t >> 6;
    int lane = t & 63;
    int row0 = blockIdx.x * 128;
    int l15  = lane & 15;
    int g4   = lane >> 4;

    f32x4 acc0[8], acc1[8];
    #pragma unroll
    for (int f = 0; f < 8; f++) {
        acc0[f] = (f32x4){0.f, 0.f, 0.f, 0.f};
        acc1[f] = (f32x4){0.f, 0.f, 0.f, 0.f};
    }

    int nstep = K >> 6;
    for (int st = 0; st < nstep; st++) {
        int kk  = st << 6;
        int seg = kk >> 7, kl = kk & 127;
        const ushort* Ap = (seg == 0) ? A0 : ((seg == 1) ? A1 : A2);

        // stage A: 1024 chunks of 16B; q = p*256+t; [ks][rb][l] order.
        #pragma unroll
        for (int p = 0; p < 4; p++) {
            int q  = p*256 + t;
            int ks = q >> 9, rb = (q >> 6) & 7, l = q & 63;
            int row = row0 + rb*16 + (l & 15);
            row = (row < N) ? row : (N - 1);
            int k = kl + ks*32 + (l >> 4)*8;
            int qbase = p*256 + w*64;
            GLD_LDS16(Ap + (size_t)row*DIM + k, As + qbase*8);
        }
        // stage B: linear copy of 16 KB from packed Bt.
        #pragma unroll
        for (int p = 0; p < 4; p++) {
            int q = p*256 + t;
            int qbase = p*256 + w*64;
            GLD_LDS16(Bt + ((size_t)st*8192 + (size_t)q*8), Bs + qbase*8);
        }
        __syncthreads();

        #pragma unroll
        for (int ks = 0; ks < 2; ks++) {
            short8 a0 = *(const short8*)(&As[((ks*8 + w*2 + 0)*64 + lane)*8]);
            short8 a1 = *(const short8*)(&As[((ks*8 + w*2 + 1)*64 + lane)*8]);
            #pragma unroll
            for (int f = 0; f < 8; f++) {
                short8 bv = *(const short8*)(&Bs[((ks*8 + f)*64 + lane)*8]);
                acc0[f] = __builtin_amdgcn_mfma_f32_16x16x32_bf16(a0, bv, acc0[f], 0, 0, 0);
                acc1[f] = __builtin_amdgcn_mfma_f32_16x16x32_bf16(a1, bv, acc1[f], 0, 0, 0);
            }
        }
        __syncthreads();
    }

    // epilogue: bias + LN + ReLU + bf16 store.
    // lane holds col = f*16+l15, rows g4*4+i of its rowblock.
    float bv[8], gv[8], bbv[8];
    #pragma unroll
    for (int f = 0; f < 8; f++) {
        bv[f]  = bias[f*16 + l15];
        gv[f]  = lng [f*16 + l15];
        bbv[f] = lnb [f*16 + l15];
    }
    #pragma unroll
    for (int r2 = 0; r2 < 2; r2++) {
        #pragma unroll
        for (int i = 0; i < 4; i++) {
            int grow = row0 + w*32 + r2*16 + g4*4 + i;
            float vv[8];
            float s = 0.f, sq = 0.f;
            #pragma unroll
            for (int f = 0; f < 8; f++) {
                float av = r2 ? acc1[f][i] : acc0[f][i];
                vv[f] = av + bv[f];
                s  += vv[f];
                sq += vv[f] * vv[f];
            }
            s += __shfl_xor(s, 1);  sq += __shfl_xor(sq, 1);
            s += __shfl_xor(s, 2);  sq += __shfl_xor(sq, 2);
            s += __shfl_xor(s, 4);  sq += __shfl_xor(sq, 4);
            s += __shfl_xor(s, 8);  sq += __shfl_xor(sq, 8);
            float m   = s * (1.f/128.f);
            float var = sq * (1.f/128.f) - m*m;
            float rr  = rsqrtf(var + 1e-5f);
            if (grow < N) {
                #pragma unroll
                for (int f = 0; f < 8; f++) {
                    float y = (vv[f] - m) * rr * gv[f] + bbv[f];
                    y = fmaxf(y, 0.f);
                    out[(size_t)grow*DIM + f*16 + l15] = f2b(y);
                }
            }
        }
    }
}

// ---------------------------------------------------------------------------
// Head: out[N][16] = xp(bf16)[N][128] @ Wh[128][16] + bh.  16 rows/block.
__global__ __launch_bounds__(256) void head_kernel(
    const ushort* __restrict__ xp, const float* __restrict__ Wh,
    const float* __restrict__ bh, float* __restrict__ out)
{
    __shared__ float Xs[16*128];
    __shared__ float Ws[128*16];
    int t = threadIdx.x;
    int row0 = blockIdx.x * 16;
    for (int i = t; i < 2048; i += 256) Ws[i] = Wh[i];
    {
        int r = t >> 4, k8 = (t & 15) * 8;
        int gr = row0 + r;
        if (gr < NPAPER) {
            uint4 v = *(const uint4*)(xp + (size_t)gr*DIM + k8);
            const ushort* pv = (const ushort*)&v;
            #pragma unroll
            for (int i = 0; i < 8; i++) Xs[r*128 + k8 + i] = b2f(pv[i]);
        } else {
            #pragma unroll
            for (int i = 0; i < 8; i++) Xs[r*128 + k8 + i] = 0.f;
        }
    }
    __syncthreads();
    int r = t >> 4, c = t & 15;
    float acc = bh[c];
    #pragma unroll 16
    for (int k = 0; k < 128; k++) acc += Xs[r*128 + k] * Ws[k*16 + c];
    int gr = row0 + r;
    if (gr < NPAPER) out[(size_t)gr*NCLS + c] = acc;
}

// ---------------------------------------------------------------------------
extern "C" void kernel_launch(void* const* d_in, const int* in_sizes, int n_in,
                              void* d_out, int out_size, void* d_ws, size_t ws_size,
                              hipStream_t stream)
{
    const float* x_paper  = (const float*)d_in[0];
    const float* x_author = (const float*)d_in[1];
    const int*   ei_cites = (const int*)d_in[2];
    const int*   ei_writes= (const int*)d_in[3];
    const int*   ei_rev   = (const int*)d_in[4];
    const float* Wl       = (const float*)d_in[5];
    const float* Wr       = (const float*)d_in[6];
    const float* bl       = (const float*)d_in[7];
    const float* linp     = (const float*)d_in[8];
    const float* lina     = (const float*)d_in[9];
    const float* ln_s     = (const float*)d_in[10];
    const float* ln_b     = (const float*)d_in[11];
    const float* Wh       = (const float*)d_in[12];
    const float* bh       = (const float*)d_in[13];
    float* out = (float*)d_out;

    float* ws = (float*)d_ws;
    size_t off = 0;
    float* Bp     = ws + off; off += 2*384*128;
    float* Ba     = ws + off; off += 2*256*128;
    float* biasp  = ws + off; off += 2*128;
    float* biasa  = ws + off; off += 2*128;
    float* biasp2 = ws + off; off += 2*128;
    float* biasa2 = ws + off; off += 2*128;

    ushort* uws = (ushort*)(ws + off);
    size_t uoff = 0;
    ushort* xpb0 = uws + uoff; uoff += (size_t)NPAPER * DIM;
    ushort* xab0 = uws + uoff; uoff += (size_t)NAUTH  * DIM;
    ushort* xpb1 = uws + uoff; uoff += (size_t)NPAPER * DIM;
    ushort* xab1 = uws + uoff; uoff += (size_t)NAUTH  * DIM;
    ushort* aggC = uws + uoff; uoff += (size_t)NPAPER * DIM;
    ushort* aggW = uws + uoff; uoff += (size_t)NPAPER * DIM;
    ushort* aggR = uws + uoff; uoff += (size_t)NAUTH  * DIM;
    ushort* Btp  = uws + uoff; uoff += 2*49152;
    ushort* Bta  = uws + uoff; uoff += 2*32768;
    if (uoff & 1) uoff++;

    int* iws = (int*)(uws + uoff);
    size_t ioff = 0;
    int* rowC = iws + ioff; ioff += NPAPER + 1;
    int* rowW = iws + ioff; ioff += NPAPER + 1;
    int* rowR = iws + ioff; ioff += NAUTH + 1;
    int* curC = iws + ioff; ioff += NPAPER;
    int* curW = iws + ioff; ioff += NPAPER;
    int* curR = iws + ioff; ioff += NAUTH;
    int* colC = iws + ioff; ioff += NEDGE;
    int* colW = iws + ioff; ioff += NEDGE;
    int* colR = iws + ioff; ioff += NEDGE;
    int* deg  = iws + ioff; ioff += NPAPER;
    int* bsum = iws + ioff; ioff += 256;

    // ---- weight prep ----
    prep_weights<<<(2*384*128 + 2*256*128 + 512 + 255)/256, 256, 0, stream>>>(
        Wl, Wr, bl, Bp, Ba, biasp, biasa);
    build_bt<<<(2*128*384 + 2*128*256 + 255)/256, 256, 0, stream>>>(
        Bp, Ba, linp, lina, Btp, Bta);
    fold_bias<<<2, 256, 0, stream>>>(biasp, biasa, linp, lina, biasp2, biasa2);

    // ---- input conversion to bf16 ----
    to_bf16<<<(NPAPER*DIM/4 + 255)/256, 256, 0, stream>>>(x_paper,  xpb0, NPAPER*DIM/4);
    to_bf16<<<(NAUTH*DIM/4 + 255)/256, 256, 0, stream>>>(x_author, xab0, NAUTH*DIM/4);

    // ---- CSR build ----
    const int* eis[3]  = { ei_cites, ei_writes, ei_rev };
    int*       rows[3] = { rowC, rowW, rowR };
    int*       curs[3] = { curC, curW, curR };
    int*       cols[3] = { colC, colW, colR };
    int        ns[3]   = { NPAPER, NPAPER, NAUTH };
    for (int tpe = 0; tpe < 3; tpe++) {
        int n  = ns[tpe];
        int nb = (n + 1023) / 1024;
        hipMemsetAsync(deg, 0, (size_t)n * 4, stream);
        deg_count<<<(NEDGE + 255)/256, 256, 0, stream>>>(eis[tpe], deg);
        scan_pass1<<<nb, 256, 0, stream>>>(deg, n, rows[tpe], bsum);
        scan_pass2<<<1, 256, 0, stream>>>(bsum, nb);
        scan_pass3<<<(n + 256)/256 + 1, 256, 0, stream>>>(rows[tpe], n, bsum, curs[tpe]);
        csr_fill<<<(NEDGE + 255)/256, 256, 0, stream>>>(eis[tpe], curs[tpe], cols[tpe]);
    }

    // ---- 2 layers ----
    for (int l = 0; l < 2; l++) {
        const ushort* cur_p = (l == 0) ? xpb0 : xpb1;
        const ushort* cur_a = (l == 0) ? xab0 : xab1;

        gather3<<<(2*NPAPER + NAUTH) * 16 / 256, 256, 0, stream>>>(
            cur_p, cur_a, rowC, colC, rowW, colW, rowR, colR, aggC, aggW, aggR);

        // paper: [meanC | meanW | x_p] (K=384), +bias, LN, ReLU -> xpb1
        gemm_ln<<<(NPAPER + 127)/128, 256, 0, stream>>>(
            aggC, aggW, cur_p, NPAPER,
            Btp + (size_t)l*49152, 384, biasp2 + l*128,
            ln_s + (l*2+0)*128, ln_b + (l*2+0)*128, xpb1);
        // author: [meanR | x_a] (K=256) -> xab1
        gemm_ln<<<(NAUTH + 127)/128, 256, 0, stream>>>(
            aggR, cur_a, nullptr, NAUTH,
            Bta + (size_t)l*32768, 256, biasa2 + l*128,
            ln_s + (l*2+1)*128, ln_b + (l*2+1)*128, xab1);
    }

    head_kernel<<<(NPAPER + 15)/16, 256, 0, stream>>>(xpb1, Wh, bh, out);
}